// Round 5
// baseline (108.515 us; speedup 1.0000x reference)
//
#include <hip/hip_runtime.h>
#include <math.h>

#define NQ 12
#define NL 4
#define NC 10
#define NB 512
#define BN_EPS 1e-5f

typedef float v2f __attribute__((ext_vector_type(2)));

// Packed complex 2x2 butterfly. Constants pre-paired:
// c0={m0,m0} c1={-m1,m1} c2={m2,m2} c3={-m3,m3} (row 0), c4..c7 row 1.
__device__ __forceinline__ void bfly(v2f& A, v2f& B,
    v2f c0, v2f c1, v2f c2, v2f c3, v2f c4, v2f c5, v2f c6, v2f c7)
{
    const v2f As = A.yx, Bs = B.yx;
    const v2f An = __builtin_elementwise_fma(c0, A,
                   __builtin_elementwise_fma(c1, As,
                   __builtin_elementwise_fma(c2, B, c3 * Bs)));
    const v2f Bn = __builtin_elementwise_fma(c4, A,
                   __builtin_elementwise_fma(c5, As,
                   __builtin_elementwise_fma(c6, B, c7 * Bs)));
    A = An; B = Bn;
}

// Round-8 resubmit (two infra failures; source re-verified, byte-identical
// plan). Barrier-free single-wave design: rounds 0/1/3 showed each
// cross-wave barrier phase costs ~3.4k cycles of WALL time regardless of
// occupancy (78k/23, 110k/31, 85k/23 cy/phase) -> eliminate barriers.
// One sample = ONE wave: 64 amps/thread (128 VGPR) x 64 lanes = 4096 amps.
// Amp bit 11-q <-> qubit q. Layout A: reg bits = amp 11..6, lane = 5..0.
// Layout B: reg bits = amp 5..0, lane = amp 11..6.
// Per layer: gates q0..5 (reg, A) -> T1 transpose -> gates q6..11 (reg, B)
// -> T2 transpose back with ring-CNOT permutation folded into addressing
// (j_m = XOR_{n>=m} i_n for m<=10; j_11 = i_11 ^ parity(i)).
// Last layer: no T2; CNOT folded into readout signs.  All LDS traffic is
// wave-private -> no cross-wave waits (single-wave block).
// Swizzles (verified all-32-banks per 16-lane quarter on BOTH sides):
//   T1: F1(i) = i ^ ((i>>6)&63)
//   T2: F2(i) = i ^ (bit9->bit0, bit8->bit1, bit7->bit2)
__global__ __launch_bounds__(64) void vqc_kernel(
    const float* __restrict__ x, const float* __restrict__ w,
    const float* __restrict__ bias, float* __restrict__ probs)
{
    __shared__ v2f stg[4096];                     // 32 KB wave-private staging
    __shared__ __align__(16) float gm[48][16];    // 48 gates x 8 paired consts

    const int b = blockIdx.x;
    const int t = threadIdx.x;                    // 0..63 = lane

    // ---- one-time: all 48 fused (Rot * RY) matrices, pre-paired/negated ----
    if (t < 48) {
        const int l = t / NQ, q = t % NQ;
        const float xq = 0.5f * x[b*NQ + q];
        const float cx = cosf(xq), sx = sinf(xq);
        const int wi = (l*NQ + q)*3;
        const float phi = w[wi], tht = w[wi+1], om = w[wi+2];
        const float ct = cosf(0.5f*tht), st = sinf(0.5f*tht);
        const float aa = 0.5f*(phi + om), dd = 0.5f*(phi - om);
        const float ca = cosf(aa), sa = sinf(aa);
        const float cd = cosf(dd), sd = sinf(dd);
        const float u00r =  ca*ct, u00i = -sa*ct;
        const float u01r = -cd*st, u01i = -sd*st;
        const float u10r =  cd*st, u10i = -sd*st;
        const float u11r =  ca*ct, u11i =  sa*ct;
        const float m00r = u00r*cx + u01r*sx, m00i = u00i*cx + u01i*sx;
        const float m01r = u01r*cx - u00r*sx, m01i = u01i*cx - u00i*sx;
        const float m10r = u10r*cx + u11r*sx, m10i = u10i*cx + u11i*sx;
        const float m11r = u11r*cx - u10r*sx, m11i = u11i*cx - u10i*sx;
        float* gp = gm[t];
        gp[0]  =  m00r; gp[1]  = m00r;
        gp[2]  = -m00i; gp[3]  = m00i;
        gp[4]  =  m01r; gp[5]  = m01r;
        gp[6]  = -m01i; gp[7]  = m01i;
        gp[8]  =  m10r; gp[9]  = m10r;
        gp[10] = -m10i; gp[11] = m10i;
        gp[12] =  m11r; gp[13] = m11r;
        gp[14] = -m11i; gp[15] = m11i;
    }
    __syncthreads();   // single-wave block: ~free (waitcnt + trivial barrier)

    // ---- per-lane constants ----
    const unsigned lane = (unsigned)t;
    const unsigned l0=lane&1u, l1=(lane>>1)&1u, l2=(lane>>2)&1u,
                   l3=(lane>>3)&1u, l4=(lane>>4)&1u, l5=(lane>>5)&1u;
    // suffix parities of lane bits: S_k = XOR_{n=k..5} lane_n
    const unsigned S5=l5, S4=S5^l4, S3=S4^l3, S2=S3^l2, S1=S2^l1, S0=S1^l0;
    // T2 (CNOT-fold) write base: jh = [j11..j6] = [S5^S0(^Pr), S4, S3, S2, S1, S0]
    const unsigned Hbase = ((S5^S0)<<5)|(S4<<4)|(S3<<3)|(S2<<2)|(S1<<1)|S0;
    const unsigned Gt    = S3 | (S2<<1) | (S1<<2);   // F2 swizzle of jh (r-indep)
    const unsigned maskP = S0 ? 63u : 0u;            // jlow = SR(r) ^ maskP
    const unsigned baseW = (Hbase<<6) | (maskP ^ Gt);
    const unsigned lane65 = lane * 65u;

    // ---- registers: layout A, amp i = (r<<6)|lane ----
    v2f a[64];
    #pragma unroll
    for (int r = 0; r < 64; ++r) a[r] = (v2f){0.f, 0.f};
    if (t == 0) a[0].x = 1.f;

    // Gate on register bit kbit, matrix row `row` of gm.
    #define GATEK(row, kbit) { \
        const v2f* cp = (const v2f*)gm[row]; \
        const v2f c0=cp[0],c1=cp[1],c2=cp[2],c3=cp[3], \
                  c4=cp[4],c5=cp[5],c6=cp[6],c7=cp[7]; \
        _Pragma("unroll") \
        for (int r0 = 0; r0 < 64; ++r0) \
            if (!(r0 & (kbit))) bfly(a[r0], a[r0|(kbit)], c0,c1,c2,c3,c4,c5,c6,c7); \
    }

    #pragma unroll 1
    for (int l = 0; l < NL; ++l) {
        const int g0 = l*12;
        // ---- stage A: reg bit k = amp bit 6+k = qubit 5-k ----
        #pragma unroll
        for (int k = 0; k < 6; ++k) GATEK(g0 + 5 - k, 1<<k)

        // ---- T1: A -> B transpose, F1(i) = i ^ ((i>>6)&63) ----
        __syncthreads();
        #pragma unroll
        for (int r = 0; r < 64; ++r) stg[lane ^ (unsigned)(65*r)] = a[r];
        __syncthreads();
        #pragma unroll
        for (int r = 0; r < 64; ++r) a[r] = stg[lane65 ^ (unsigned)r];

        // ---- stage B: reg bit k = amp bit k = qubit 11-k ----
        #pragma unroll
        for (int k = 0; k < 6; ++k) GATEK(g0 + 11 - k, 1<<k)

        if (l < NL-1) {
            // ---- T2: B -> A' with ring CNOT folded; store at F2(j) ----
            __syncthreads();
            #pragma unroll
            for (int r = 0; r < 64; ++r) {
                const unsigned r5=((unsigned)r>>5)&1u, r4=((unsigned)r>>4)&1u,
                               r3=((unsigned)r>>3)&1u, r2=((unsigned)r>>2)&1u,
                               r1=((unsigned)r>>1)&1u, r0b=(unsigned)r&1u;
                const unsigned SR5=r5, SR4=SR5^r4, SR3=SR4^r3,
                               SR2=SR3^r2, SR1=SR2^r1, SR0=SR1^r0b;  // Pr=SR0
                const unsigned SRval = SR0|(SR1<<1)|(SR2<<2)|(SR3<<3)|(SR4<<4)|(SR5<<5);
                stg[baseW ^ ((SR0<<11) ^ SRval)] = a[r];
            }
            __syncthreads();
            #pragma unroll
            for (int r = 0; r < 64; ++r) {
                const unsigned gp = (((unsigned)r>>3)&1u)
                                  | ((((unsigned)r>>2)&1u)<<1)
                                  | ((((unsigned)r>>1)&1u)<<2);
                a[r] = stg[lane ^ (((unsigned)r<<6) | gp)];
            }
        }
    }

    // ---- readout from layout B; last ring CNOT folded into signs ----
    // class c reads final bit 11-c:
    //  c0: S5^S0 ^ Pr(r) | c1..c5: S4,S3,S2,S1,S0 | c6..c9: S0 ^ SR{5,4,3,2}(r)
    float psum=0.f, fP=0.f, f5=0.f, f4=0.f, f3=0.f, f2=0.f;
    #pragma unroll
    for (int r = 0; r < 64; ++r) {
        const float p = a[r].x*a[r].x + a[r].y*a[r].y;
        const unsigned r5=((unsigned)r>>5)&1u, r4=((unsigned)r>>4)&1u,
                       r3=((unsigned)r>>3)&1u, r2=((unsigned)r>>2)&1u,
                       r1=((unsigned)r>>1)&1u, r0b=(unsigned)r&1u;
        const unsigned sr4=r4^r5, sr3=r3^sr4, sr2=r2^sr3, pr=sr2^r1^r0b;
        psum += p;
        fP += pr  ? -p : p;
        f5 += r5  ? -p : p;
        f4 += sr4 ? -p : p;
        f3 += sr3 ? -p : p;
        f2 += sr2 ? -p : p;
    }
    const float sA0=(S5^S0)?-1.f:1.f, sq1=S4?-1.f:1.f, sq2=S3?-1.f:1.f,
                sq3=S2?-1.f:1.f, sq4=S1?-1.f:1.f, sq5=S0?-1.f:1.f;
    float acc[NC];
    acc[0]=sA0*fP;   acc[1]=sq1*psum; acc[2]=sq2*psum; acc[3]=sq3*psum;
    acc[4]=sq4*psum; acc[5]=sq5*psum; acc[6]=sq5*f5;   acc[7]=sq5*f4;
    acc[8]=sq5*f3;   acc[9]=sq5*f2;

    #pragma unroll
    for (int off = 32; off >= 1; off >>= 1) {
        #pragma unroll
        for (int c = 0; c < NC; ++c)
            acc[c] += __shfl_down(acc[c], off, 64);
    }
    if (t == 0) {
        float ez[NC];
        float mx = -1e30f;
        #pragma unroll
        for (int c = 0; c < NC; ++c) {
            ez[c] = acc[c] + bias[c];
            mx = fmaxf(mx, ez[c]);
        }
        float sum = 0.f;
        #pragma unroll
        for (int c = 0; c < NC; ++c) { ez[c] = expf(ez[c] - mx); sum += ez[c]; }
        const float inv = 1.f / sum;
        #pragma unroll
        for (int c = 0; c < NC; ++c) probs[b*NC + c] = ez[c] * inv;
    }
}

// BatchNorm1d (training mode, biased var) over the batch dim, in place on d_out.
__global__ __launch_bounds__(256) void bn_kernel(
    float* __restrict__ probs, const float* __restrict__ gamma,
    const float* __restrict__ beta)
{
    const int c = blockIdx.x;
    const int t = threadIdx.x;
    const float v0 = probs[t*NC + c];
    const float v1 = probs[(t + 256)*NC + c];
    float s  = v0 + v1;
    float ss = v0*v0 + v1*v1;
    #pragma unroll
    for (int off = 32; off >= 1; off >>= 1) {
        s  += __shfl_down(s,  off, 64);
        ss += __shfl_down(ss, off, 64);
    }
    __shared__ float sm[8];
    __shared__ float stat[2];
    const int wave = t >> 6, lane = t & 63;
    if (lane == 0) { sm[wave] = s; sm[4 + wave] = ss; }
    __syncthreads();
    if (t == 0) {
        const float S  = sm[0] + sm[1] + sm[2] + sm[3];
        const float SS = sm[4] + sm[5] + sm[6] + sm[7];
        const float mu  = S * (1.f/512.f);
        const float var = SS * (1.f/512.f) - mu*mu;
        stat[0] = mu;
        stat[1] = 1.f / sqrtf(var + BN_EPS);
    }
    __syncthreads();
    const float mu = stat[0], inv = stat[1];
    const float g = gamma[c], bt = beta[c];
    probs[t*NC + c]         = (v0 - mu) * inv * g + bt;
    probs[(t + 256)*NC + c] = (v1 - mu) * inv * g + bt;
}

extern "C" void kernel_launch(void* const* d_in, const int* in_sizes, int n_in,
                              void* d_out, int out_size, void* d_ws, size_t ws_size,
                              hipStream_t stream) {
    const float* x     = (const float*)d_in[0];   // (512, 12)
    const float* w     = (const float*)d_in[1];   // (4, 12, 3)
    const float* bias  = (const float*)d_in[2];   // (10,)
    const float* gamma = (const float*)d_in[3];   // (10,)
    const float* beta  = (const float*)d_in[4];   // (10,)
    float* out = (float*)d_out;                   // (512, 10) float32

    vqc_kernel<<<NB, 64, 0, stream>>>(x, w, bias, out);
    bn_kernel<<<NC, 256, 0, stream>>>(out, gamma, beta);
}